// Round 14
// baseline (278.463 us; speedup 1.0000x reference)
//
#include <hip/hip_runtime.h>

// Problem constants
#define BB    2
#define HN    8
#define NSEQ  2048
#define DIMM  1536
#define DKD   64
#define DVD   192
#define QCOLS 512        // HN*DKD
#define VCOLS 1536       // HN*DVD

typedef short short8 __attribute__((ext_vector_type(8)));
typedef float f32x4  __attribute__((ext_vector_type(4)));
typedef unsigned short ushortT;

static __device__ inline ushortT f2bf(float f) {
    unsigned u = __builtin_bit_cast(unsigned, f);
    u = (u + 0x7FFFu + ((u >> 16) & 1u)) >> 16;
    return (ushortT)u;
}

// async global -> LDS, 16B per lane. LDS dest = wave-uniform base + lane*16.
static __device__ inline void gl_lds16(const ushortT* g, ushortT* l) {
    __builtin_amdgcn_global_load_lds(
        (const __attribute__((address_space(1))) unsigned int*)g,
        (__attribute__((address_space(3))) unsigned int*)l, 16, 0, 0);
}

// HW waitcnt + COMPILER memory fence in one.
#define FENCE_VM0()    asm volatile("s_waitcnt vmcnt(0)" ::: "memory")
#define FENCE_VM3()    asm volatile("s_waitcnt vmcnt(3)" ::: "memory")
#define FENCE_VM7()    asm volatile("s_waitcnt vmcnt(7)" ::: "memory")
#define FENCE_VM12()   asm volatile("s_waitcnt vmcnt(12)" ::: "memory")
#define FENCE_VM16()   asm volatile("s_waitcnt vmcnt(16)" ::: "memory")
#define FENCE_LGKM0()  asm volatile("s_waitcnt lgkmcnt(0)" ::: "memory")
#define FENCE_SOFT()   asm volatile("" ::: "memory")

// ---------------------------------------------------------------------------
// Prep (single launch): region-decoded by blockIdx.x  (unchanged)
// ---------------------------------------------------------------------------
__global__ __launch_bounds__(256)
void prep_kernel(const float* __restrict__ x,
                 const float* __restrict__ Wq, const float* __restrict__ Wk,
                 const float* __restrict__ Wv, const float* __restrict__ Wo,
                 ushortT* __restrict__ xb, ushortT* __restrict__ wqkv,
                 ushortT* __restrict__ wo_t)
{
    __shared__ ushortT tt[32][33];
    const int b = blockIdx.x, tid = threadIdx.x;

    if (b < 3072) {
        const size_t idx = (size_t)b * 256 + tid;
        const float4* p = (const float4*)x + idx * 2;
        const float4 a = p[0], c = p[1];
        short8 v;
        v[0] = f2bf(a.x); v[1] = f2bf(a.y); v[2] = f2bf(a.z); v[3] = f2bf(a.w);
        v[4] = f2bf(c.x); v[5] = f2bf(c.y); v[6] = f2bf(c.z); v[7] = f2bf(c.w);
        *(short8*)(xb + idx * 8) = v;
        return;
    }

    const float* W; ushortT* Wt; int ncols, t;
    if (b < 3840)      { W = Wq; Wt = wqkv;                          ncols = QCOLS; t = b - 3072; }
    else if (b < 4608) { W = Wk; Wt = wqkv + (size_t)QCOLS * DIMM;   ncols = QCOLS; t = b - 3840; }
    else if (b < 6912) { W = Wv; Wt = wqkv + (size_t)2*QCOLS * DIMM; ncols = VCOLS; t = b - 4608; }
    else               { W = Wo; Wt = wo_t;                          ncols = DIMM;  t = b - 6912; }

    const int nbx = ncols >> 5;
    const int c0 = (t % nbx) * 32, k0 = (t / nbx) * 32;
    const int lx = tid & 31, ly = tid >> 5;
    #pragma unroll
    for (int r = 0; r < 4; r++)
        tt[ly + r * 8][lx] = f2bf(W[(size_t)(k0 + ly + r * 8) * ncols + c0 + lx]);
    __syncthreads();
    #pragma unroll
    for (int r = 0; r < 4; r++)
        Wt[(size_t)(c0 + ly + r * 8) * DIMM + k0 + lx] = tt[lx][ly + r * 8];
}

// ---------------------------------------------------------------------------
// GEMM (R0 structure, best measured; unchanged — frozen at shape ceiling).
// v_ws key-slot permutation (R5); q_ws pre-scaled by log2(e) (R11).
// ---------------------------------------------------------------------------
__global__ __launch_bounds__(256)
void gemm_kernel(const ushortT* __restrict__ A, const ushortT* __restrict__ Bt,
                 const float* __restrict__ bo,
                 const float* __restrict__ pos, const float* __restrict__ rcb,
                 ushortT* __restrict__ q_ws, ushortT* __restrict__ k_ws,
                 ushortT* __restrict__ v_ws, float* __restrict__ Cout, int mode)
{
    __shared__ ushortT As[128 * 64];   // 16 KB
    __shared__ ushortT Bs[64 * 64];    //  8 KB

    const int tid  = threadIdx.x;
    const int wave = tid >> 6, lane = tid & 63;
    const int quad = lane >> 4, l15 = lane & 15;
    const int m0 = blockIdx.y * 128, n0 = blockIdx.x * 64;

    const int sl_r = lane >> 3;
    const int sl_c = ((lane & 7) ^ sl_r) * 8;

    const ushortT* Ab = A  + (size_t)m0 * DIMM;
    const ushortT* Bb = Bt + (size_t)n0 * DIMM;

    f32x4 acc[2][4];
    #pragma unroll
    for (int i = 0; i < 2; i++)
        #pragma unroll
        for (int j = 0; j < 4; j++) acc[i][j] = (f32x4){0.f, 0.f, 0.f, 0.f};

    for (int k0 = 0; k0 < DIMM; k0 += 64) {
        #pragma unroll
        for (int t = 0; t < 4; t++) {
            const int g = wave * 4 + t;
            gl_lds16(Ab + (size_t)(g * 8 + sl_r) * DIMM + k0 + sl_c, &As[g * 512]);
        }
        #pragma unroll
        for (int t = 0; t < 2; t++) {
            const int g = wave * 2 + t;
            gl_lds16(Bb + (size_t)(g * 8 + sl_r) * DIMM + k0 + sl_c, &Bs[g * 512]);
        }
        __syncthreads();

        short8 af[2][2], bf[4][2];
        #pragma unroll
        for (int i = 0; i < 2; i++) {
            const int r = wave * 32 + i * 16 + l15;
            #pragma unroll
            for (int ks = 0; ks < 2; ks++)
                af[i][ks] = *(const short8*)&As[r * 64 + (((ks * 4 + quad) ^ (l15 & 7)) * 8)];
        }
        #pragma unroll
        for (int j = 0; j < 4; j++) {
            const int r = j * 16 + l15;
            #pragma unroll
            for (int ks = 0; ks < 2; ks++)
                bf[j][ks] = *(const short8*)&Bs[r * 64 + (((ks * 4 + quad) ^ (l15 & 7)) * 8)];
        }

        #pragma unroll
        for (int ks = 0; ks < 2; ks++)
            #pragma unroll
            for (int i = 0; i < 2; i++)
                #pragma unroll
                for (int j = 0; j < 4; j++)
                    acc[i][j] = __builtin_amdgcn_mfma_f32_16x16x32_bf16(af[i][ks], bf[j][ks], acc[i][j], 0, 0, 0);

        __syncthreads();
    }

    #pragma unroll
    for (int i = 0; i < 2; i++) {
        #pragma unroll
        for (int j = 0; j < 4; j++) {
            const int gcol = n0 + j * 16 + l15;
            #pragma unroll
            for (int r = 0; r < 4; r++) {
                const int grow = m0 + wave * 32 + i * 16 + quad * 4 + r;
                const float val = acc[i][j][r];
                if (mode == 1) {
                    Cout[(size_t)grow * DIMM + gcol] = val + bo[gcol];
                } else {
                    const int b = grow >> 11, n = grow & (NSEQ - 1);
                    if (gcol < QCOLS) {
                        const int h = gcol >> 6, d = gcol & 63;
                        // log2(e) folded in: flash computes exp2(s - SHIFT2)
                        q_ws[((size_t)(b * HN + h) * NSEQ + n) * DKD + d] =
                            f2bf((val * 0.125f + pos[((size_t)h * NSEQ + n) * DKD + d] + rcb[h * DKD + d])
                                 * 1.4426950408889634f);
                    } else if (gcol < 2 * QCOLS) {
                        const int c = gcol - QCOLS, h = c >> 6, d = c & 63;
                        k_ws[((size_t)(b * HN + h) * NSEQ + n) * DKD + d] = f2bf(val);
                    } else {
                        const int c = gcol - 2 * QCOLS, h = c / DVD, d = c - h * DVD;
                        // interleaved key-slot within each 32-key group
                        const int p = (n & ~31) | (((n & 15) << 1) | ((n >> 4) & 1));
                        v_ws[((size_t)(b * HN + h) * DVD + d) * NSEQ + p] = f2bf(val);   // [b,h,d,slot]
                    }
                }
            }
        }
    }
}

// ---------------------------------------------------------------------------
// Flash R14: R13's K-dbuf one-round-ahead schedule, TRIMMED to 34816 B so
// 4 blocks/CU actually fit (R13's 40960 B silently dropped residency to ~3
// — per-block throughput improved 20% but occupancy loss ate it).
// Trim: V LDS tile = 9 of 12 gl_lds (d rows 0..143); nt2=9..11 V-frags
// load DIRECT to registers at round start (full-round latency cover;
// unlike R10's failed version, no mid-round issue and vmcnt order keeps
// K(t+1) in flight). Per round t (par = t&1):
//   lgkm0 -> V_lds(9) -> V_reg(3) -> K(t+1)(4) into Kbuf[par^1]
//   [outstanding oldest->newest: K(t)4, V_lds9, V_reg3, K(t+1)4 = 20]
//   -> vmcnt(16): K(t) done (staged a full round ago — no exposed wait)
//   -> QK from Kbuf[par] -> softmax, P overlays Kbuf[par] (R12 trick)
//   -> vmcnt(7): V_lds done; V_reg+K(t+1) in flight
//   -> PV nt2=0..8 from LDS; nt2=9..11 from regs (compiler emits vmcnt(4)
//      before their MFMAs — drains V_reg, K(t+1) STAYS in flight).
// Last round: no K-issue -> vmcnt(12)/vmcnt(3)/compiler vmcnt(0).
// Per-wave LDS: Kdbuf 2x2048 + V 4608 = 8704 shorts; block 34816 B < 37888
// (proven 4-blocks size). Packed P (R5) + V-swizzle (R8) + exp2 (R11).
// ---------------------------------------------------------------------------
#define PLD2 40
#define SHIFT2 28.8539008178f   // 20 * log2(e)

__global__ __launch_bounds__(128)
void flash_kernel(const ushortT* __restrict__ q_ws, const ushortT* __restrict__ k_ws,
                  const ushortT* __restrict__ v_ws, ushortT* __restrict__ attn)
{
    // per-wave 8704 shorts: Kbuf[0] [0,2048), Kbuf[1] [2048,4096),
    // V_lds [4096,8704). P overlays Kbuf[t&1] after QK.
    // Epilogue reuse: ox f32[96*64] = shorts [0,12288), lx [12288,13312).
    __shared__ ushortT lds[2 * 8704];

    const int tid = threadIdx.x;
    const int wave = tid >> 6, lane = tid & 63;
    const int quad = lane >> 4, l15 = lane & 15;

    const int bh = blockIdx.x & 15;        // XCD-affine: bh's blocks share L2
    const int qt = blockIdx.x >> 4;
    const int n0 = qt * 32;
    const int b  = bh >> 3, h = bh & 7;

    const ushortT* kg = k_ws + (size_t)bh * NSEQ * DKD + (size_t)(wave * 1024) * DKD;
    const ushortT* vg = v_ws + (size_t)bh * DVD * NSEQ + wave * 1024;

    ushortT* st = lds + wave * 8704;           // Kbuf[2] then V_lds

    // staging source swizzles
    const int k_r = lane >> 3, k_c = ((lane & 7) ^ (k_r & 7)) * 8;        // K: 8 rows x 8 chunks
    const int v_r = lane >> 2;
    const int v_c = ((lane & 3) ^ ((v_r >> 1) & 3)) * 8;                  // V: 16 rows x 4 chunks, (row>>1) swizzle

    // direct V fragment base (nt2=9..11): row d = nt2*16 + l15, slots quad*8..+7
    const ushortT* vb = vg + (size_t)l15 * NSEQ + quad * 8;

    // Q A-frags (resident): qf[mt][ks], rows n0 + mt*16 + l15
    short8 qf[2][2];
    #pragma unroll
    for (int mt = 0; mt < 2; mt++)
        #pragma unroll
        for (int ks = 0; ks < 2; ks++)
            qf[mt][ks] = *(const short8*)(q_ws + ((size_t)bh * NSEQ + n0 + mt * 16 + l15) * DKD + ks * 32 + quad * 8);

    f32x4 o[2][12];
    #pragma unroll
    for (int mt = 0; mt < 2; mt++)
        #pragma unroll
        for (int nt = 0; nt < 12; nt++) o[mt][nt] = (f32x4){0.f, 0.f, 0.f, 0.f};

    float l_part[2][4];
    #pragma unroll
    for (int mt = 0; mt < 2; mt++)
        #pragma unroll
        for (int i = 0; i < 4; i++) l_part[mt][i] = 0.f;

    // prologue: stage K(0) into Kbuf[0] (waited by round-0's vmcnt(16))
    #pragma unroll
    for (int t = 0; t < 4; t++)
        gl_lds16(kg + (size_t)(t * 8 + k_r) * DKD + k_c, st + t * 512);

    for (int kt0 = 0; kt0 < 1024; kt0 += 32) {
        const int par = (kt0 >> 5) & 1;
        ushortT* kb = st + par * 2048;         // current K tile (and P overlay)

        // all prior ds_reads/writes on this wave's buffers must be retired
        FENCE_LGKM0();

        #pragma unroll
        for (int u = 0; u < 9; u++)       // V_lds: d rows 0..143
            gl_lds16(vg + (size_t)(u * 16 + v_r) * NSEQ + kt0 + v_c, st + 4096 + u * 512);

        FENCE_SOFT();   // pin V_reg issue AFTER V_lds (vmcnt ordering)

        short8 vfr[3];                    // direct V frags, nt2 = 9..11
        #pragma unroll
        for (int j = 0; j < 3; j++)
            vfr[j] = *(const short8*)(vb + (size_t)((9 + j) * 16) * NSEQ + kt0);

        FENCE_SOFT();   // pin K(t+1) issue AFTER V_reg

        const bool more = (kt0 + 32 < 1024);
        if (more) {
            #pragma unroll
            for (int t = 0; t < 4; t++)   // K(t+1) -> other buffer
                gl_lds16(kg + (size_t)(kt0 + 32 + t * 8 + k_r) * DKD + k_c,
                         st + (par ^ 1) * 2048 + t * 512);
            FENCE_VM16();  // K(t) done; V_lds+V_reg+K(t+1)=16 may remain
        } else {
            FENCE_VM12();  // K(31) done; V_lds+V_reg=12 may remain
        }

        // ---- S = Q @ K^T (K staged a full round ago — no exposed wait) ----
        f32x4 s[2][2];
        #pragma unroll
        for (int mt = 0; mt < 2; mt++)
            #pragma unroll
            for (int nt = 0; nt < 2; nt++) s[mt][nt] = (f32x4){0.f, 0.f, 0.f, 0.f};
        #pragma unroll
        for (int ks = 0; ks < 2; ks++)
            #pragma unroll
            for (int nt = 0; nt < 2; nt++) {
                const int key = nt * 16 + l15;
                short8 kf = *(const short8*)&kb[key * 64 + (((ks * 4 + quad) ^ (key & 7)) * 8)];
                s[0][nt] = __builtin_amdgcn_mfma_f32_16x16x32_bf16(qf[0][ks], kf, s[0][nt], 0, 0, 0);
                s[1][nt] = __builtin_amdgcn_mfma_f32_16x16x32_bf16(qf[1][ks], kf, s[1][nt], 0, 0, 0);
            }

        // ---- p = exp2(s - SHIFT2); row-sum partials; PACKED P store ----
        // (P overlays kb — per-wave DS ordering: QK reads issued first)
        #pragma unroll
        for (int mt = 0; mt < 2; mt++)
            #pragma unroll
            for (int i = 0; i < 4; i++) {
                const float p0 = __builtin_amdgcn_exp2f(s[mt][0][i] - SHIFT2);
                const float p1 = __builtin_amdgcn_exp2f(s[mt][1][i] - SHIFT2);
                l_part[mt][i] += p0 + p1;
                unsigned pk;
                asm("v_cvt_pk_bf16_f32 %0, %1, %2" : "=v"(pk) : "v"(p0), "v"(p1));
                *(unsigned*)&kb[(mt * 16 + quad * 4 + i) * PLD2 + 2 * l15] = pk;
            }

        FENCE_SOFT();  // cross-lane P write->read dep is invisible per-lane

        short8 a[2];
        #pragma unroll
        for (int mt = 0; mt < 2; mt++)
            a[mt] = *(const short8*)&kb[(mt * 16 + l15) * PLD2 + quad * 8];

        if (more) { FENCE_VM7(); }   // V_lds landed; V_reg+K(t+1) in flight
        else      { FENCE_VM3(); }   // V_lds landed; V_reg in flight

        // ---- O += P @ V: nt2 0..8 from LDS, 9..11 from registers ----
        #pragma unroll
        for (int nt2 = 0; nt2 < 9; nt2++) {
            const int d = nt2 * 16 + l15;
            short8 vf = *(const short8*)&st[4096 + d * 32 + ((quad ^ ((l15 >> 1) & 3)) * 8)];
            o[0][nt2] = __builtin_amdgcn_mfma_f32_16x16x32_bf16(a[0], vf, o[0][nt2], 0, 0, 0);
            o[1][nt2] = __builtin_amdgcn_mfma_f32_16x16x32_bf16(a[1], vf, o[1][nt2], 0, 0, 0);
        }
        #pragma unroll
        for (int j = 0; j < 3; j++) {     // compiler waits vmcnt(4): V_reg done,
            o[0][9 + j] = __builtin_amdgcn_mfma_f32_16x16x32_bf16(a[0], vfr[j], o[0][9 + j], 0, 0, 0);
            o[1][9 + j] = __builtin_amdgcn_mfma_f32_16x16x32_bf16(a[1], vfr[j], o[1][9 + j], 0, 0, 0);
        }                                 // K(t+1) stays in flight
    }

    // ---- reduce l over the 16 key-lanes ----
    #pragma unroll
    for (int off = 1; off <= 8; off <<= 1)
        #pragma unroll
        for (int mt = 0; mt < 2; mt++)
            #pragma unroll
            for (int i = 0; i < 4; i++)
                l_part[mt][i] += __shfl_xor(l_part[mt][i], off, 64);

    // ---- combine key-half partials in LDS; wave 0 finalizes ----
    __syncthreads();
    float* ox = (float*)lds;              // 96 slots x 64 lanes = 24576 B
    float* lx = (float*)(lds + 12288);    // 8 slots x 64 lanes = 2048 B
    if (wave == 1) {
        #pragma unroll
        for (int mt = 0; mt < 2; mt++)
            #pragma unroll
            for (int nt2 = 0; nt2 < 12; nt2++)
                #pragma unroll
                for (int i = 0; i < 4; i++)
                    ox[(((mt * 12 + nt2) * 4 + i) * 64) + lane] = o[mt][nt2][i];
        #pragma unroll
        for (int mt = 0; mt < 2; mt++)
            #pragma unroll
            for (int i = 0; i < 4; i++)
                lx[(mt * 4 + i) * 64 + lane] = l_part[mt][i];
    }
    __syncthreads();
    if (wave == 0) {
        float inv[2][4];
        #pragma unroll
        for (int mt = 0; mt < 2; mt++)
            #pragma unroll
            for (int i = 0; i < 4; i++)
                inv[mt][i] = 1.f / (l_part[mt][i] + lx[(mt * 4 + i) * 64 + lane]);
        #pragma unroll
        for (int mt = 0; mt < 2; mt++)
            #pragma unroll
            for (int nt2 = 0; nt2 < 12; nt2++)
                #pragma unroll
                for (int i = 0; i < 4; i++) {
                    const float v = o[mt][nt2][i] + ox[(((mt * 12 + nt2) * 4 + i) * 64) + lane];
                    const int n = n0 + mt * 16 + quad * 4 + i;
                    attn[((size_t)b * NSEQ + n) * DIMM + h * DVD + nt2 * 16 + l15] =
                        f2bf(v * inv[mt][i]);
                }
    }
}

// ---------------------------------------------------------------------------
extern "C" void kernel_launch(void* const* d_in, const int* in_sizes, int n_in,
                              void* d_out, int out_size, void* d_ws, size_t ws_size,
                              hipStream_t stream)
{
    const float* x   = (const float*)d_in[0];
    const float* Wq  = (const float*)d_in[1];
    const float* Wk  = (const float*)d_in[2];
    const float* Wv  = (const float*)d_in[3];
    const float* Wo  = (const float*)d_in[4];
    const float* bo  = (const float*)d_in[5];
    const float* pos = (const float*)d_in[6];
    const float* rcb = (const float*)d_in[7];
    float* out = (float*)d_out;

    ushortT* xb    = (ushortT*)d_ws;                             // 4096*1536
    ushortT* wqkv  = xb    + (size_t)4096 * DIMM;                // 2560*1536
    ushortT* wo_t  = wqkv  + (size_t)(2 * QCOLS + VCOLS) * DIMM; // 1536*1536
    ushortT* q_ws  = wo_t  + (size_t)DIMM * DIMM;
    ushortT* k_ws  = q_ws  + (size_t)BB * HN * NSEQ * DKD;
    ushortT* v_ws  = k_ws  + (size_t)BB * HN * NSEQ * DKD;       // V^T [b,h,d,slot]
    ushortT* attnb = v_ws  + (size_t)BB * HN * NSEQ * DVD;       // 4096*1536

    prep_kernel<<<dim3(9216), dim3(256), 0, stream>>>(x, Wq, Wk, Wv, Wo, xb, wqkv, wo_t);

    gemm_kernel<<<dim3(40, 32), dim3(256), 0, stream>>>(xb, wqkv, bo, pos, rcb,
                                                        q_ws, k_ws, v_ws, nullptr, 0);
    flash_kernel<<<dim3(1024), dim3(128), 0, stream>>>(q_ws, k_ws, v_ws, attnb);
    gemm_kernel<<<dim3(24, 32), dim3(256), 0, stream>>>(attnb, wo_t, bo, pos, rcb,
                                                        q_ws, k_ws, v_ws, out, 1);
}

// Round 15
// 260.356 us; speedup vs baseline: 1.0695x; 1.0695x over previous
//
#include <hip/hip_runtime.h>

// Problem constants
#define BB    2
#define HN    8
#define NSEQ  2048
#define DIMM  1536
#define DKD   64
#define DVD   192
#define QCOLS 512        // HN*DKD
#define VCOLS 1536       // HN*DVD

typedef short short8 __attribute__((ext_vector_type(8)));
typedef float f32x4  __attribute__((ext_vector_type(4)));
typedef unsigned short ushortT;

static __device__ inline ushortT f2bf(float f) {
    unsigned u = __builtin_bit_cast(unsigned, f);
    u = (u + 0x7FFFu + ((u >> 16) & 1u)) >> 16;
    return (ushortT)u;
}

// async global -> LDS, 16B per lane. LDS dest = wave-uniform base + lane*16.
static __device__ inline void gl_lds16(const ushortT* g, ushortT* l) {
    __builtin_amdgcn_global_load_lds(
        (const __attribute__((address_space(1))) unsigned int*)g,
        (__attribute__((address_space(3))) unsigned int*)l, 16, 0, 0);
}

// HW waitcnt + COMPILER memory fence in one.
#define FENCE_VM0()    asm volatile("s_waitcnt vmcnt(0)" ::: "memory")
#define FENCE_VM12()   asm volatile("s_waitcnt vmcnt(12)" ::: "memory")
#define FENCE_LGKM0()  asm volatile("s_waitcnt lgkmcnt(0)" ::: "memory")
#define FENCE_SOFT()   asm volatile("" ::: "memory")

// ---------------------------------------------------------------------------
// Prep (single launch): region-decoded by blockIdx.x  (unchanged)
// ---------------------------------------------------------------------------
__global__ __launch_bounds__(256)
void prep_kernel(const float* __restrict__ x,
                 const float* __restrict__ Wq, const float* __restrict__ Wk,
                 const float* __restrict__ Wv, const float* __restrict__ Wo,
                 ushortT* __restrict__ xb, ushortT* __restrict__ wqkv,
                 ushortT* __restrict__ wo_t)
{
    __shared__ ushortT tt[32][33];
    const int b = blockIdx.x, tid = threadIdx.x;

    if (b < 3072) {
        const size_t idx = (size_t)b * 256 + tid;
        const float4* p = (const float4*)x + idx * 2;
        const float4 a = p[0], c = p[1];
        short8 v;
        v[0] = f2bf(a.x); v[1] = f2bf(a.y); v[2] = f2bf(a.z); v[3] = f2bf(a.w);
        v[4] = f2bf(c.x); v[5] = f2bf(c.y); v[6] = f2bf(c.z); v[7] = f2bf(c.w);
        *(short8*)(xb + idx * 8) = v;
        return;
    }

    const float* W; ushortT* Wt; int ncols, t;
    if (b < 3840)      { W = Wq; Wt = wqkv;                          ncols = QCOLS; t = b - 3072; }
    else if (b < 4608) { W = Wk; Wt = wqkv + (size_t)QCOLS * DIMM;   ncols = QCOLS; t = b - 3840; }
    else if (b < 6912) { W = Wv; Wt = wqkv + (size_t)2*QCOLS * DIMM; ncols = VCOLS; t = b - 4608; }
    else               { W = Wo; Wt = wo_t;                          ncols = DIMM;  t = b - 6912; }

    const int nbx = ncols >> 5;
    const int c0 = (t % nbx) * 32, k0 = (t / nbx) * 32;
    const int lx = tid & 31, ly = tid >> 5;
    #pragma unroll
    for (int r = 0; r < 4; r++)
        tt[ly + r * 8][lx] = f2bf(W[(size_t)(k0 + ly + r * 8) * ncols + c0 + lx]);
    __syncthreads();
    #pragma unroll
    for (int r = 0; r < 4; r++)
        Wt[(size_t)(c0 + ly + r * 8) * DIMM + k0 + lx] = tt[lx][ly + r * 8];
}

// ---------------------------------------------------------------------------
// GEMM (R0 structure, best measured; unchanged — frozen at shape ceiling).
// v_ws key-slot permutation (R5); q_ws pre-scaled by log2(e) (R11).
// ---------------------------------------------------------------------------
__global__ __launch_bounds__(256)
void gemm_kernel(const ushortT* __restrict__ A, const ushortT* __restrict__ Bt,
                 const float* __restrict__ bo,
                 const float* __restrict__ pos, const float* __restrict__ rcb,
                 ushortT* __restrict__ q_ws, ushortT* __restrict__ k_ws,
                 ushortT* __restrict__ v_ws, float* __restrict__ Cout, int mode)
{
    __shared__ ushortT As[128 * 64];   // 16 KB
    __shared__ ushortT Bs[64 * 64];    //  8 KB

    const int tid  = threadIdx.x;
    const int wave = tid >> 6, lane = tid & 63;
    const int quad = lane >> 4, l15 = lane & 15;
    const int m0 = blockIdx.y * 128, n0 = blockIdx.x * 64;

    const int sl_r = lane >> 3;
    const int sl_c = ((lane & 7) ^ sl_r) * 8;

    const ushortT* Ab = A  + (size_t)m0 * DIMM;
    const ushortT* Bb = Bt + (size_t)n0 * DIMM;

    f32x4 acc[2][4];
    #pragma unroll
    for (int i = 0; i < 2; i++)
        #pragma unroll
        for (int j = 0; j < 4; j++) acc[i][j] = (f32x4){0.f, 0.f, 0.f, 0.f};

    for (int k0 = 0; k0 < DIMM; k0 += 64) {
        #pragma unroll
        for (int t = 0; t < 4; t++) {
            const int g = wave * 4 + t;
            gl_lds16(Ab + (size_t)(g * 8 + sl_r) * DIMM + k0 + sl_c, &As[g * 512]);
        }
        #pragma unroll
        for (int t = 0; t < 2; t++) {
            const int g = wave * 2 + t;
            gl_lds16(Bb + (size_t)(g * 8 + sl_r) * DIMM + k0 + sl_c, &Bs[g * 512]);
        }
        __syncthreads();

        short8 af[2][2], bf[4][2];
        #pragma unroll
        for (int i = 0; i < 2; i++) {
            const int r = wave * 32 + i * 16 + l15;
            #pragma unroll
            for (int ks = 0; ks < 2; ks++)
                af[i][ks] = *(const short8*)&As[r * 64 + (((ks * 4 + quad) ^ (l15 & 7)) * 8)];
        }
        #pragma unroll
        for (int j = 0; j < 4; j++) {
            const int r = j * 16 + l15;
            #pragma unroll
            for (int ks = 0; ks < 2; ks++)
                bf[j][ks] = *(const short8*)&Bs[r * 64 + (((ks * 4 + quad) ^ (l15 & 7)) * 8)];
        }

        #pragma unroll
        for (int ks = 0; ks < 2; ks++)
            #pragma unroll
            for (int i = 0; i < 2; i++)
                #pragma unroll
                for (int j = 0; j < 4; j++)
                    acc[i][j] = __builtin_amdgcn_mfma_f32_16x16x32_bf16(af[i][ks], bf[j][ks], acc[i][j], 0, 0, 0);

        __syncthreads();
    }

    #pragma unroll
    for (int i = 0; i < 2; i++) {
        #pragma unroll
        for (int j = 0; j < 4; j++) {
            const int gcol = n0 + j * 16 + l15;
            #pragma unroll
            for (int r = 0; r < 4; r++) {
                const int grow = m0 + wave * 32 + i * 16 + quad * 4 + r;
                const float val = acc[i][j][r];
                if (mode == 1) {
                    Cout[(size_t)grow * DIMM + gcol] = val + bo[gcol];
                } else {
                    const int b = grow >> 11, n = grow & (NSEQ - 1);
                    if (gcol < QCOLS) {
                        const int h = gcol >> 6, d = gcol & 63;
                        // log2(e) folded in: flash computes exp2(s - SHIFT2)
                        q_ws[((size_t)(b * HN + h) * NSEQ + n) * DKD + d] =
                            f2bf((val * 0.125f + pos[((size_t)h * NSEQ + n) * DKD + d] + rcb[h * DKD + d])
                                 * 1.4426950408889634f);
                    } else if (gcol < 2 * QCOLS) {
                        const int c = gcol - QCOLS, h = c >> 6, d = c & 63;
                        k_ws[((size_t)(b * HN + h) * NSEQ + n) * DKD + d] = f2bf(val);
                    } else {
                        const int c = gcol - 2 * QCOLS, h = c / DVD, d = c - h * DVD;
                        // interleaved key-slot within each 32-key group
                        const int p = (n & ~31) | (((n & 15) << 1) | ((n >> 4) & 1));
                        v_ws[((size_t)(b * HN + h) * DVD + d) * NSEQ + p] = f2bf(val);   // [b,h,d,slot]
                    }
                }
            }
        }
    }
}

// ---------------------------------------------------------------------------
// Flash (R12 = best measured config, 256.2 us total) + T5 s_setprio.
// Grid 1024 = 16 bh (XCD-affine) x 64 q-tiles of 32 rows. Block = 2 waves.
// Wave w: keys [w*1024, +1024), KT=32, 32 rounds, PRIVATE 16KB K/V staging;
// per-wave self-sync: lgkm0 -> stage K(4)+V(12) -> vmcnt(12) -> QK/softmax/P
// -> vmcnt(0) -> PV. Key-half partials combined via one LDS exchange at end.
// P-in-K-region (R12): after QK's ds_reads the 4KB K tile is dead for the
// round; P (2.5KB) overlays it. LDS 32768 B = exactly 5 blocks/CU.
// Packed P (R5), V-swizzle quad^((d>>1)&3) both sides (R8), exp2 (R11).
// T5 (R15): s_setprio(1) around the QK and PV MFMA clusters — flash's
// waves are barrier-free and phase-staggered (the m191 attn regime where
// setprio measured +4-7%; null only in barrier-lockstep GEMM, m190).
// R13/R14 K-dbuf family abandoned: occupancy collapse tracked the
// schedule, not LDS size (34816B still 9.5%); direct-V regs re-failed.
// ---------------------------------------------------------------------------
#define PLD2 40
#define SHIFT2 28.8539008178f   // 20 * log2(e)

__global__ __launch_bounds__(128)
void flash_kernel(const ushortT* __restrict__ q_ws, const ushortT* __restrict__ k_ws,
                  const ushortT* __restrict__ v_ws, ushortT* __restrict__ attn)
{
    // [0,16384) shorts = 32 KB: per-wave staging (wave*8192: K 2048 shorts
    // [P reuses first 1280 after QK], V 6144 shorts).
    // Epilogue reuse: ox f32[96*64] = shorts [0,12288), lx = [12288,13312).
    __shared__ ushortT lds[16384];

    const int tid = threadIdx.x;
    const int wave = tid >> 6, lane = tid & 63;
    const int quad = lane >> 4, l15 = lane & 15;

    const int bh = blockIdx.x & 15;        // XCD-affine: bh's blocks share L2
    const int qt = blockIdx.x >> 4;
    const int n0 = qt * 32;
    const int b  = bh >> 3, h = bh & 7;

    const ushortT* kg = k_ws + (size_t)bh * NSEQ * DKD + (size_t)(wave * 1024) * DKD;
    const ushortT* vg = v_ws + (size_t)bh * DVD * NSEQ + wave * 1024;

    ushortT* st = lds + wave * 8192;           // K at [0,2048), V at [2048,8192)
    ushortT* Pw = st;                          // P overlays dead K region

    // staging source swizzles
    const int k_r = lane >> 3, k_c = ((lane & 7) ^ (k_r & 7)) * 8;        // K: 8 rows x 8 chunks
    const int v_r = lane >> 2;
    const int v_c = ((lane & 3) ^ ((v_r >> 1) & 3)) * 8;                  // V: 16 rows x 4 chunks, (row>>1) swizzle

    // Q A-frags (resident): qf[mt][ks], rows n0 + mt*16 + l15
    short8 qf[2][2];
    #pragma unroll
    for (int mt = 0; mt < 2; mt++)
        #pragma unroll
        for (int ks = 0; ks < 2; ks++)
            qf[mt][ks] = *(const short8*)(q_ws + ((size_t)bh * NSEQ + n0 + mt * 16 + l15) * DKD + ks * 32 + quad * 8);

    f32x4 o[2][12];
    #pragma unroll
    for (int mt = 0; mt < 2; mt++)
        #pragma unroll
        for (int nt = 0; nt < 12; nt++) o[mt][nt] = (f32x4){0.f, 0.f, 0.f, 0.f};

    float l_part[2][4];
    #pragma unroll
    for (int mt = 0; mt < 2; mt++)
        #pragma unroll
        for (int i = 0; i < 4; i++) l_part[mt][i] = 0.f;

    for (int kt0 = 0; kt0 < 1024; kt0 += 32) {
        // all prior ds_reads on this wave's buffers must be retired
        FENCE_LGKM0();

        #pragma unroll
        for (int t = 0; t < 4; t++)       // K tile: 32 keys x 64 d = 4 KB
            gl_lds16(kg + (size_t)(kt0 + t * 8 + k_r) * DKD + k_c, st + t * 512);
        #pragma unroll
        for (int u = 0; u < 12; u++)      // V^T tile: 192 d x 32 key-slots = 12 KB
            gl_lds16(vg + (size_t)(u * 16 + v_r) * NSEQ + kt0 + v_c, st + 2048 + u * 512);

        FENCE_VM12();  // 4 oldest (K) landed; V still in flight

        // ---- S = Q @ K^T ----
        f32x4 s[2][2];
        #pragma unroll
        for (int mt = 0; mt < 2; mt++)
            #pragma unroll
            for (int nt = 0; nt < 2; nt++) s[mt][nt] = (f32x4){0.f, 0.f, 0.f, 0.f};
        __builtin_amdgcn_s_setprio(1);
        #pragma unroll
        for (int ks = 0; ks < 2; ks++)
            #pragma unroll
            for (int nt = 0; nt < 2; nt++) {
                const int key = nt * 16 + l15;
                short8 kf = *(const short8*)&st[key * 64 + (((ks * 4 + quad) ^ (key & 7)) * 8)];
                s[0][nt] = __builtin_amdgcn_mfma_f32_16x16x32_bf16(qf[0][ks], kf, s[0][nt], 0, 0, 0);
                s[1][nt] = __builtin_amdgcn_mfma_f32_16x16x32_bf16(qf[1][ks], kf, s[1][nt], 0, 0, 0);
            }
        __builtin_amdgcn_s_setprio(0);

        // ---- p = exp2(s - SHIFT2); row-sum partials; PACKED P store ----
        // (writes overlay the K region — per-wave DS ordering makes this safe)
        #pragma unroll
        for (int mt = 0; mt < 2; mt++)
            #pragma unroll
            for (int i = 0; i < 4; i++) {
                const float p0 = __builtin_amdgcn_exp2f(s[mt][0][i] - SHIFT2);
                const float p1 = __builtin_amdgcn_exp2f(s[mt][1][i] - SHIFT2);
                l_part[mt][i] += p0 + p1;
                unsigned pk;
                asm("v_cvt_pk_bf16_f32 %0, %1, %2" : "=v"(pk) : "v"(p0), "v"(p1));
                *(unsigned*)&Pw[(mt * 16 + quad * 4 + i) * PLD2 + 2 * l15] = pk;
            }

        FENCE_SOFT();  // cross-lane P write->read dep is invisible per-lane

        short8 a[2];
        #pragma unroll
        for (int mt = 0; mt < 2; mt++)
            a[mt] = *(const short8*)&Pw[(mt * 16 + l15) * PLD2 + quad * 8];

        FENCE_VM0();   // V landed

        // ---- O += P @ V (k-slots permuted identically on both operands) ----
        __builtin_amdgcn_s_setprio(1);
        #pragma unroll
        for (int nt2 = 0; nt2 < 12; nt2++) {
            const int d = nt2 * 16 + l15;
            short8 vf = *(const short8*)&st[2048 + d * 32 + ((quad ^ ((l15 >> 1) & 3)) * 8)];
            o[0][nt2] = __builtin_amdgcn_mfma_f32_16x16x32_bf16(a[0], vf, o[0][nt2], 0, 0, 0);
            o[1][nt2] = __builtin_amdgcn_mfma_f32_16x16x32_bf16(a[1], vf, o[1][nt2], 0, 0, 0);
        }
        __builtin_amdgcn_s_setprio(0);
    }

    // ---- reduce l over the 16 key-lanes ----
    #pragma unroll
    for (int off = 1; off <= 8; off <<= 1)
        #pragma unroll
        for (int mt = 0; mt < 2; mt++)
            #pragma unroll
            for (int i = 0; i < 4; i++)
                l_part[mt][i] += __shfl_xor(l_part[mt][i], off, 64);

    // ---- combine key-half partials in LDS; wave 0 finalizes ----
    __syncthreads();
    float* ox = (float*)lds;              // 96 slots x 64 lanes = 24576 B
    float* lx = (float*)(lds + 12288);    // 8 slots x 64 lanes = 2048 B
    if (wave == 1) {
        #pragma unroll
        for (int mt = 0; mt < 2; mt++)
            #pragma unroll
            for (int nt2 = 0; nt2 < 12; nt2++)
                #pragma unroll
                for (int i = 0; i < 4; i++)
                    ox[(((mt * 12 + nt2) * 4 + i) * 64) + lane] = o[mt][nt2][i];
        #pragma unroll
        for (int mt = 0; mt < 2; mt++)
            #pragma unroll
            for (int i = 0; i < 4; i++)
                lx[(mt * 4 + i) * 64 + lane] = l_part[mt][i];
    }
    __syncthreads();
    if (wave == 0) {
        float inv[2][4];
        #pragma unroll
        for (int mt = 0; mt < 2; mt++)
            #pragma unroll
            for (int i = 0; i < 4; i++)
                inv[mt][i] = 1.f / (l_part[mt][i] + lx[(mt * 4 + i) * 64 + lane]);
        #pragma unroll
        for (int mt = 0; mt < 2; mt++)
            #pragma unroll
            for (int nt2 = 0; nt2 < 12; nt2++)
                #pragma unroll
                for (int i = 0; i < 4; i++) {
                    const float v = o[mt][nt2][i] + ox[(((mt * 12 + nt2) * 4 + i) * 64) + lane];
                    const int n = n0 + mt * 16 + quad * 4 + i;
                    attn[((size_t)b * NSEQ + n) * DIMM + h * DVD + nt2 * 16 + l15] =
                        f2bf(v * inv[mt][i]);
                }
    }
}

// ---------------------------------------------------------------------------
extern "C" void kernel_launch(void* const* d_in, const int* in_sizes, int n_in,
                              void* d_out, int out_size, void* d_ws, size_t ws_size,
                              hipStream_t stream)
{
    const float* x   = (const float*)d_in[0];
    const float* Wq  = (const float*)d_in[1];
    const float* Wk  = (const float*)d_in[2];
    const float* Wv  = (const float*)d_in[3];
    const float* Wo  = (const float*)d_in[4];
    const float* bo  = (const float*)d_in[5];
    const float* pos = (const float*)d_in[6];
    const float* rcb = (const float*)d_in[7];
    float* out = (float*)d_out;

    ushortT* xb    = (ushortT*)d_ws;                             // 4096*1536
    ushortT* wqkv  = xb    + (size_t)4096 * DIMM;                // 2560*1536
    ushortT* wo_t  = wqkv  + (size_t)(2 * QCOLS + VCOLS) * DIMM; // 1536*1536
    ushortT* q_ws  = wo_t  + (size_t)DIMM * DIMM;
    ushortT* k_ws  = q_ws  + (size_t)BB * HN * NSEQ * DKD;
    ushortT* v_ws  = k_ws  + (size_t)BB * HN * NSEQ * DKD;       // V^T [b,h,d,slot]
    ushortT* attnb = v_ws  + (size_t)BB * HN * NSEQ * DVD;       // 4096*1536

    prep_kernel<<<dim3(9216), dim3(256), 0, stream>>>(x, Wq, Wk, Wv, Wo, xb, wqkv, wo_t);

    gemm_kernel<<<dim3(40, 32), dim3(256), 0, stream>>>(xb, wqkv, bo, pos, rcb,
                                                        q_ws, k_ws, v_ws, nullptr, 0);
    flash_kernel<<<dim3(1024), dim3(128), 0, stream>>>(q_ws, k_ws, v_ws, attnb);
    gemm_kernel<<<dim3(24, 32), dim3(256), 0, stream>>>(attnb, wo_t, bo, pos, rcb,
                                                        q_ws, k_ws, v_ws, out, 1);
}

// Round 16
// 258.960 us; speedup vs baseline: 1.0753x; 1.0054x over previous
//
#include <hip/hip_runtime.h>

// Problem constants
#define BB    2
#define HN    8
#define NSEQ  2048
#define DIMM  1536
#define DKD   64
#define DVD   192
#define QCOLS 512        // HN*DKD
#define VCOLS 1536       // HN*DVD

typedef short short8 __attribute__((ext_vector_type(8)));
typedef float f32x4  __attribute__((ext_vector_type(4)));
typedef unsigned short ushortT;

static __device__ inline ushortT f2bf(float f) {
    unsigned u = __builtin_bit_cast(unsigned, f);
    u = (u + 0x7FFFu + ((u >> 16) & 1u)) >> 16;
    return (ushortT)u;
}

// async global -> LDS, 16B per lane. LDS dest = wave-uniform base + lane*16.
static __device__ inline void gl_lds16(const ushortT* g, ushortT* l) {
    __builtin_amdgcn_global_load_lds(
        (const __attribute__((address_space(1))) unsigned int*)g,
        (__attribute__((address_space(3))) unsigned int*)l, 16, 0, 0);
}

// HW waitcnt + COMPILER memory fence in one.
#define FENCE_VM0()    asm volatile("s_waitcnt vmcnt(0)" ::: "memory")
#define FENCE_VM12()   asm volatile("s_waitcnt vmcnt(12)" ::: "memory")
#define FENCE_LGKM0()  asm volatile("s_waitcnt lgkmcnt(0)" ::: "memory")
#define FENCE_SOFT()   asm volatile("" ::: "memory")

// ---------------------------------------------------------------------------
// Prep (single launch): region-decoded by blockIdx.x  (unchanged)
// ---------------------------------------------------------------------------
__global__ __launch_bounds__(256)
void prep_kernel(const float* __restrict__ x,
                 const float* __restrict__ Wq, const float* __restrict__ Wk,
                 const float* __restrict__ Wv, const float* __restrict__ Wo,
                 ushortT* __restrict__ xb, ushortT* __restrict__ wqkv,
                 ushortT* __restrict__ wo_t)
{
    __shared__ ushortT tt[32][33];
    const int b = blockIdx.x, tid = threadIdx.x;

    if (b < 3072) {
        const size_t idx = (size_t)b * 256 + tid;
        const float4* p = (const float4*)x + idx * 2;
        const float4 a = p[0], c = p[1];
        short8 v;
        v[0] = f2bf(a.x); v[1] = f2bf(a.y); v[2] = f2bf(a.z); v[3] = f2bf(a.w);
        v[4] = f2bf(c.x); v[5] = f2bf(c.y); v[6] = f2bf(c.z); v[7] = f2bf(c.w);
        *(short8*)(xb + idx * 8) = v;
        return;
    }

    const float* W; ushortT* Wt; int ncols, t;
    if (b < 3840)      { W = Wq; Wt = wqkv;                          ncols = QCOLS; t = b - 3072; }
    else if (b < 4608) { W = Wk; Wt = wqkv + (size_t)QCOLS * DIMM;   ncols = QCOLS; t = b - 3840; }
    else if (b < 6912) { W = Wv; Wt = wqkv + (size_t)2*QCOLS * DIMM; ncols = VCOLS; t = b - 4608; }
    else               { W = Wo; Wt = wo_t;                          ncols = DIMM;  t = b - 6912; }

    const int nbx = ncols >> 5;
    const int c0 = (t % nbx) * 32, k0 = (t / nbx) * 32;
    const int lx = tid & 31, ly = tid >> 5;
    #pragma unroll
    for (int r = 0; r < 4; r++)
        tt[ly + r * 8][lx] = f2bf(W[(size_t)(k0 + ly + r * 8) * ncols + c0 + lx]);
    __syncthreads();
    #pragma unroll
    for (int r = 0; r < 4; r++)
        Wt[(size_t)(c0 + ly + r * 8) * DIMM + k0 + lx] = tt[lx][ly + r * 8];
}

// ---------------------------------------------------------------------------
// GEMM (R0 structure, best measured; frozen at its m102 shape ceiling —
// 5 alternative schedules all landed 83-96 us): BM=128, BN=64, BK=64;
// 4 waves, each 32x64 out, acc[2][4]; single-buffered, 2 barriers/K-step.
// LDS 24 KB. v_ws key-slot permutation (R5): key n -> slot
// 2*(n&15)|((n>>4)&1) within each 32-key group (matches flash's packed
// P-store). q_ws pre-scaled by log2(e) (R11) so flash uses v_exp_f32.
// ---------------------------------------------------------------------------
__global__ __launch_bounds__(256)
void gemm_kernel(const ushortT* __restrict__ A, const ushortT* __restrict__ Bt,
                 const float* __restrict__ bo,
                 const float* __restrict__ pos, const float* __restrict__ rcb,
                 ushortT* __restrict__ q_ws, ushortT* __restrict__ k_ws,
                 ushortT* __restrict__ v_ws, float* __restrict__ Cout, int mode)
{
    __shared__ ushortT As[128 * 64];   // 16 KB
    __shared__ ushortT Bs[64 * 64];    //  8 KB

    const int tid  = threadIdx.x;
    const int wave = tid >> 6, lane = tid & 63;
    const int quad = lane >> 4, l15 = lane & 15;
    const int m0 = blockIdx.y * 128, n0 = blockIdx.x * 64;

    const int sl_r = lane >> 3;
    const int sl_c = ((lane & 7) ^ sl_r) * 8;

    const ushortT* Ab = A  + (size_t)m0 * DIMM;
    const ushortT* Bb = Bt + (size_t)n0 * DIMM;

    f32x4 acc[2][4];
    #pragma unroll
    for (int i = 0; i < 2; i++)
        #pragma unroll
        for (int j = 0; j < 4; j++) acc[i][j] = (f32x4){0.f, 0.f, 0.f, 0.f};

    for (int k0 = 0; k0 < DIMM; k0 += 64) {
        #pragma unroll
        for (int t = 0; t < 4; t++) {
            const int g = wave * 4 + t;
            gl_lds16(Ab + (size_t)(g * 8 + sl_r) * DIMM + k0 + sl_c, &As[g * 512]);
        }
        #pragma unroll
        for (int t = 0; t < 2; t++) {
            const int g = wave * 2 + t;
            gl_lds16(Bb + (size_t)(g * 8 + sl_r) * DIMM + k0 + sl_c, &Bs[g * 512]);
        }
        __syncthreads();

        short8 af[2][2], bf[4][2];
        #pragma unroll
        for (int i = 0; i < 2; i++) {
            const int r = wave * 32 + i * 16 + l15;
            #pragma unroll
            for (int ks = 0; ks < 2; ks++)
                af[i][ks] = *(const short8*)&As[r * 64 + (((ks * 4 + quad) ^ (l15 & 7)) * 8)];
        }
        #pragma unroll
        for (int j = 0; j < 4; j++) {
            const int r = j * 16 + l15;
            #pragma unroll
            for (int ks = 0; ks < 2; ks++)
                bf[j][ks] = *(const short8*)&Bs[r * 64 + (((ks * 4 + quad) ^ (l15 & 7)) * 8)];
        }

        #pragma unroll
        for (int ks = 0; ks < 2; ks++)
            #pragma unroll
            for (int i = 0; i < 2; i++)
                #pragma unroll
                for (int j = 0; j < 4; j++)
                    acc[i][j] = __builtin_amdgcn_mfma_f32_16x16x32_bf16(af[i][ks], bf[j][ks], acc[i][j], 0, 0, 0);

        __syncthreads();
    }

    #pragma unroll
    for (int i = 0; i < 2; i++) {
        #pragma unroll
        for (int j = 0; j < 4; j++) {
            const int gcol = n0 + j * 16 + l15;
            #pragma unroll
            for (int r = 0; r < 4; r++) {
                const int grow = m0 + wave * 32 + i * 16 + quad * 4 + r;
                const float val = acc[i][j][r];
                if (mode == 1) {
                    Cout[(size_t)grow * DIMM + gcol] = val + bo[gcol];
                } else {
                    const int b = grow >> 11, n = grow & (NSEQ - 1);
                    if (gcol < QCOLS) {
                        const int h = gcol >> 6, d = gcol & 63;
                        // log2(e) folded in: flash computes exp2(s - SHIFT2)
                        q_ws[((size_t)(b * HN + h) * NSEQ + n) * DKD + d] =
                            f2bf((val * 0.125f + pos[((size_t)h * NSEQ + n) * DKD + d] + rcb[h * DKD + d])
                                 * 1.4426950408889634f);
                    } else if (gcol < 2 * QCOLS) {
                        const int c = gcol - QCOLS, h = c >> 6, d = c & 63;
                        k_ws[((size_t)(b * HN + h) * NSEQ + n) * DKD + d] = f2bf(val);
                    } else {
                        const int c = gcol - 2 * QCOLS, h = c / DVD, d = c - h * DVD;
                        // interleaved key-slot within each 32-key group
                        const int p = (n & ~31) | (((n & 15) << 1) | ((n >> 4) & 1));
                        v_ws[((size_t)(b * HN + h) * DVD + d) * NSEQ + p] = f2bf(val);   // [b,h,d,slot]
                    }
                }
            }
        }
    }
}

// ---------------------------------------------------------------------------
// Flash (R12 = best measured config, 256.2 us total — FINAL).
// Grid 1024 = 16 bh (XCD-affine) x 64 q-tiles of 32 rows. Block = 2 waves.
// Wave w: keys [w*1024, +1024), KT=32, 32 rounds, PRIVATE 16KB K/V staging;
// per-wave self-sync: lgkm0 -> stage K(4)+V(12) -> vmcnt(12) -> QK/softmax/P
// -> vmcnt(0) -> PV. Key-half partials combined via one LDS exchange at end.
// P-in-K-region (R12): after QK's ds_reads the 4KB K tile is dead for the
// round; P (2.5KB) overlays it. LDS 32768 B = exactly 5 blocks/CU.
// Packed P (R5): interleaved v_ws key slots -> one v_cvt_pk_bf16_f32 +
// one ds_write_b32 per P-row pair. V-swizzle (R8): chunk quad^((d>>1)&3)
// both sides -> 2-way = free (conflicts 3.67M -> 524K measured).
// exp2 (R11): p = exp2(s - SHIFT2) via __builtin_amdgcn_exp2f.
// Session ledger: failed families (do not retry): key-split removal (R3),
// K-reg prefetch (R4), BK=32 (R6), direct-V regs (R10/R14), K-dbuf
// counted-vmcnt (R13/R14), setprio (R15 null).
// ---------------------------------------------------------------------------
#define PLD2 40
#define SHIFT2 28.8539008178f   // 20 * log2(e)

__global__ __launch_bounds__(128)
void flash_kernel(const ushortT* __restrict__ q_ws, const ushortT* __restrict__ k_ws,
                  const ushortT* __restrict__ v_ws, ushortT* __restrict__ attn)
{
    // [0,16384) shorts = 32 KB: per-wave staging (wave*8192: K 2048 shorts
    // [P reuses first 1280 after QK], V 6144 shorts).
    // Epilogue reuse: ox f32[96*64] = shorts [0,12288), lx = [12288,13312).
    __shared__ ushortT lds[16384];

    const int tid = threadIdx.x;
    const int wave = tid >> 6, lane = tid & 63;
    const int quad = lane >> 4, l15 = lane & 15;

    const int bh = blockIdx.x & 15;        // XCD-affine: bh's blocks share L2
    const int qt = blockIdx.x >> 4;
    const int n0 = qt * 32;
    const int b  = bh >> 3, h = bh & 7;

    const ushortT* kg = k_ws + (size_t)bh * NSEQ * DKD + (size_t)(wave * 1024) * DKD;
    const ushortT* vg = v_ws + (size_t)bh * DVD * NSEQ + wave * 1024;

    ushortT* st = lds + wave * 8192;           // K at [0,2048), V at [2048,8192)
    ushortT* Pw = st;                          // P overlays dead K region

    // staging source swizzles
    const int k_r = lane >> 3, k_c = ((lane & 7) ^ (k_r & 7)) * 8;        // K: 8 rows x 8 chunks
    const int v_r = lane >> 2;
    const int v_c = ((lane & 3) ^ ((v_r >> 1) & 3)) * 8;                  // V: 16 rows x 4 chunks, (row>>1) swizzle

    // Q A-frags (resident): qf[mt][ks], rows n0 + mt*16 + l15
    short8 qf[2][2];
    #pragma unroll
    for (int mt = 0; mt < 2; mt++)
        #pragma unroll
        for (int ks = 0; ks < 2; ks++)
            qf[mt][ks] = *(const short8*)(q_ws + ((size_t)bh * NSEQ + n0 + mt * 16 + l15) * DKD + ks * 32 + quad * 8);

    f32x4 o[2][12];
    #pragma unroll
    for (int mt = 0; mt < 2; mt++)
        #pragma unroll
        for (int nt = 0; nt < 12; nt++) o[mt][nt] = (f32x4){0.f, 0.f, 0.f, 0.f};

    float l_part[2][4];
    #pragma unroll
    for (int mt = 0; mt < 2; mt++)
        #pragma unroll
        for (int i = 0; i < 4; i++) l_part[mt][i] = 0.f;

    for (int kt0 = 0; kt0 < 1024; kt0 += 32) {
        // all prior ds_reads on this wave's buffers must be retired
        FENCE_LGKM0();

        #pragma unroll
        for (int t = 0; t < 4; t++)       // K tile: 32 keys x 64 d = 4 KB
            gl_lds16(kg + (size_t)(kt0 + t * 8 + k_r) * DKD + k_c, st + t * 512);
        #pragma unroll
        for (int u = 0; u < 12; u++)      // V^T tile: 192 d x 32 key-slots = 12 KB
            gl_lds16(vg + (size_t)(u * 16 + v_r) * NSEQ + kt0 + v_c, st + 2048 + u * 512);

        FENCE_VM12();  // 4 oldest (K) landed; V still in flight

        // ---- S = Q @ K^T ----
        f32x4 s[2][2];
        #pragma unroll
        for (int mt = 0; mt < 2; mt++)
            #pragma unroll
            for (int nt = 0; nt < 2; nt++) s[mt][nt] = (f32x4){0.f, 0.f, 0.f, 0.f};
        #pragma unroll
        for (int ks = 0; ks < 2; ks++)
            #pragma unroll
            for (int nt = 0; nt < 2; nt++) {
                const int key = nt * 16 + l15;
                short8 kf = *(const short8*)&st[key * 64 + (((ks * 4 + quad) ^ (key & 7)) * 8)];
                s[0][nt] = __builtin_amdgcn_mfma_f32_16x16x32_bf16(qf[0][ks], kf, s[0][nt], 0, 0, 0);
                s[1][nt] = __builtin_amdgcn_mfma_f32_16x16x32_bf16(qf[1][ks], kf, s[1][nt], 0, 0, 0);
            }

        // ---- p = exp2(s - SHIFT2); row-sum partials; PACKED P store ----
        // (writes overlay the K region — per-wave DS ordering makes this safe)
        #pragma unroll
        for (int mt = 0; mt < 2; mt++)
            #pragma unroll
            for (int i = 0; i < 4; i++) {
                const float p0 = __builtin_amdgcn_exp2f(s[mt][0][i] - SHIFT2);
                const float p1 = __builtin_amdgcn_exp2f(s[mt][1][i] - SHIFT2);
                l_part[mt][i] += p0 + p1;
                unsigned pk;
                asm("v_cvt_pk_bf16_f32 %0, %1, %2" : "=v"(pk) : "v"(p0), "v"(p1));
                *(unsigned*)&Pw[(mt * 16 + quad * 4 + i) * PLD2 + 2 * l15] = pk;
            }

        FENCE_SOFT();  // cross-lane P write->read dep is invisible per-lane

        short8 a[2];
        #pragma unroll
        for (int mt = 0; mt < 2; mt++)
            a[mt] = *(const short8*)&Pw[(mt * 16 + l15) * PLD2 + quad * 8];

        FENCE_VM0();   // V landed

        // ---- O += P @ V (k-slots permuted identically on both operands) ----
        #pragma unroll
        for (int nt2 = 0; nt2 < 12; nt2++) {
            const int d = nt2 * 16 + l15;
            short8 vf = *(const short8*)&st[2048 + d * 32 + ((quad ^ ((l15 >> 1) & 3)) * 8)];
            o[0][nt2] = __builtin_amdgcn_mfma_f32_16x16x32_bf16(a[0], vf, o[0][nt2], 0, 0, 0);
            o[1][nt2] = __builtin_amdgcn_mfma_f32_16x16x32_bf16(a[1], vf, o[1][nt2], 0, 0, 0);
        }
    }

    // ---- reduce l over the 16 key-lanes ----
    #pragma unroll
    for (int off = 1; off <= 8; off <<= 1)
        #pragma unroll
        for (int mt = 0; mt < 2; mt++)
            #pragma unroll
            for (int i = 0; i < 4; i++)
                l_part[mt][i] += __shfl_xor(l_part[mt][i], off, 64);

    // ---- combine key-half partials in LDS; wave 0 finalizes ----
    __syncthreads();
    float* ox = (float*)lds;              // 96 slots x 64 lanes = 24576 B
    float* lx = (float*)(lds + 12288);    // 8 slots x 64 lanes = 2048 B
    if (wave == 1) {
        #pragma unroll
        for (int mt = 0; mt < 2; mt++)
            #pragma unroll
            for (int nt2 = 0; nt2 < 12; nt2++)
                #pragma unroll
                for (int i = 0; i < 4; i++)
                    ox[(((mt * 12 + nt2) * 4 + i) * 64) + lane] = o[mt][nt2][i];
        #pragma unroll
        for (int mt = 0; mt < 2; mt++)
            #pragma unroll
            for (int i = 0; i < 4; i++)
                lx[(mt * 4 + i) * 64 + lane] = l_part[mt][i];
    }
    __syncthreads();
    if (wave == 0) {
        float inv[2][4];
        #pragma unroll
        for (int mt = 0; mt < 2; mt++)
            #pragma unroll
            for (int i = 0; i < 4; i++)
                inv[mt][i] = 1.f / (l_part[mt][i] + lx[(mt * 4 + i) * 64 + lane]);
        #pragma unroll
        for (int mt = 0; mt < 2; mt++)
            #pragma unroll
            for (int nt2 = 0; nt2 < 12; nt2++)
                #pragma unroll
                for (int i = 0; i < 4; i++) {
                    const float v = o[mt][nt2][i] + ox[(((mt * 12 + nt2) * 4 + i) * 64) + lane];
                    const int n = n0 + mt * 16 + quad * 4 + i;
                    attn[((size_t)b * NSEQ + n) * DIMM + h * DVD + nt2 * 16 + l15] =
                        f2bf(v * inv[mt][i]);
                }
    }
}

// ---------------------------------------------------------------------------
extern "C" void kernel_launch(void* const* d_in, const int* in_sizes, int n_in,
                              void* d_out, int out_size, void* d_ws, size_t ws_size,
                              hipStream_t stream)
{
    const float* x   = (const float*)d_in[0];
    const float* Wq  = (const float*)d_in[1];
    const float* Wk  = (const float*)d_in[2];
    const float* Wv  = (const float*)d_in[3];
    const float* Wo  = (const float*)d_in[4];
    const float* bo  = (const float*)d_in[5];
    const float* pos = (const float*)d_in[6];
    const float* rcb = (const float*)d_in[7];
    float* out = (float*)d_out;

    ushortT* xb    = (ushortT*)d_ws;                             // 4096*1536
    ushortT* wqkv  = xb    + (size_t)4096 * DIMM;                // 2560*1536
    ushortT* wo_t  = wqkv  + (size_t)(2 * QCOLS + VCOLS) * DIMM; // 1536*1536
    ushortT* q_ws  = wo_t  + (size_t)DIMM * DIMM;
    ushortT* k_ws  = q_ws  + (size_t)BB * HN * NSEQ * DKD;
    ushortT* v_ws  = k_ws  + (size_t)BB * HN * NSEQ * DKD;       // V^T [b,h,d,slot]
    ushortT* attnb = v_ws  + (size_t)BB * HN * NSEQ * DVD;       // 4096*1536

    prep_kernel<<<dim3(9216), dim3(256), 0, stream>>>(x, Wq, Wk, Wv, Wo, xb, wqkv, wo_t);

    gemm_kernel<<<dim3(40, 32), dim3(256), 0, stream>>>(xb, wqkv, bo, pos, rcb,
                                                        q_ws, k_ws, v_ws, nullptr, 0);
    flash_kernel<<<dim3(1024), dim3(128), 0, stream>>>(q_ws, k_ws, v_ws, attnb);
    gemm_kernel<<<dim3(24, 32), dim3(256), 0, stream>>>(attnb, wo_t, bo, pos, rcb,
                                                        q_ws, k_ws, v_ws, out, 1);
}